// Round 11
// baseline (247.795 us; speedup 1.0000x reference)
//
#include <hip/hip_runtime.h>

#define DEV __device__ __forceinline__

// ---------------- constants ----------------
// N_NODES=32768, N_EDGES=65536, H=8, D=64, DS=63, M=128, R=H*N=262144
#define NNODES 32768
#define NEDGES 65536
#define NROWS  262144
#define EPSF   1e-7f
#define SQRT2F 1.4142135623730951f
#define LOG2E  1.4426950408889634f
#define LOG2SQRT63 2.9886399611087573f   // log2(sqrt(63))

// ---------------- ws layout (bytes) ----------------
// Sequenced reuse: Wfrag (k01->k2) then lastB (k3p->k45) share offset 0.
#define OFF_WFRAG 0u          // bf16 [3][8][2][4][64][8]  W in MFMA B-frag order (196608 B) [dead after k2]
#define OFF_LASTB 0u          // bf8  [8][4][4][64][8] B-frag of last (65536 B) [written k3p, read k45]
#define OFF_PFRAG 196608u     // bf16 [8][2][64][8]  sqrt(2)*log2e*P, MFMA A-frag order (16384 B)
#define OFF_EA    212992u     // float ea + uint done-counter (zeroed by k01)
#define OFF_U     409600u     // bf16 [N][64] u (4194304 B) [dead after k2]
#define OFF_PART  42352640u   // bf16 [256 c][8 h][64 d][128 m] split-K partials of last (33554432 B)
#define OFF_PHIQ  75907072u   // fp8 e4m3 [R][128] (33554432 B)
#define OFF_PHIK  143015936u  // fp8 e4m3 [R][128] (33554432 B)

typedef short s8v __attribute__((ext_vector_type(8)));   // 8 bf16 in 4 VGPRs (MFMA A/B frag)
typedef float f4v __attribute__((ext_vector_type(4)));   // MFMA C/D frag
typedef float f2v __attribute__((ext_vector_type(2)));

// ---------------- helpers ----------------
DEV unsigned short f2bf(float f) {  // rne
  unsigned u = __float_as_uint(f);
  return (unsigned short)((u + 0x7fffu + ((u >> 16) & 1u)) >> 16);
}
DEV float bf2f(unsigned short h) { return __uint_as_float(((unsigned)h) << 16); }
// pack two f32 -> two bf16 (round-half-up) in one uint: low short = bf16(lo), high = bf16(hi)
DEV unsigned pack2(float lo, float hi) {
  return __builtin_amdgcn_perm(__float_as_uint(hi) + 0x8000u, __float_as_uint(lo) + 0x8000u, 0x07060302u);
}
DEV float frcp(float x) { return __builtin_amdgcn_rcpf(x); }
DEV float fsqrt(float x) { return __builtin_amdgcn_sqrtf(x); }    // raw v_sqrt_f32, args in normal range
DEV float fexp2(float x) { return __builtin_amdgcn_exp2f(x); }    // raw v_exp_f32, args in normal range

// ---------------- K01: u cast (+ blocks<96: pack W/P frags; block0: zero ea/cnt) ----------------
// u = logmap0(proj(expmap0(z))) == [0, z[1:]] identically (acosh(cosh t)=t for t~0.08).
__global__ __launch_bounds__(256) void k01_prep(const float* __restrict__ z, unsigned short* __restrict__ ubf,
                                                const float* __restrict__ Wq, const float* __restrict__ Wk,
                                                const float* __restrict__ Wv, const float* __restrict__ P,
                                                unsigned short* __restrict__ Wfrag, unsigned short* __restrict__ Pfrag,
                                                float* __restrict__ ea) {
  int i = blockIdx.x * 256 + threadIdx.x;  // 524288 float4 groups
  float4 v = *(const float4*)(z + (size_t)i * 4);
  if ((i & 15) == 0) v.x = 0.f;  // time slot
  uint2 pk;
  pk.x = pack2(v.x, v.y);
  pk.y = pack2(v.z, v.w);
  *(uint2*)(ubf + (size_t)i * 4) = pk;

  if (blockIdx.x < 96) {
    if (i == 0) { ea[0] = 0.f; ((unsigned*)ea)[1] = 0u; }
    int stride = 96 * 256;
    // Wfrag[sm][h][ks][nt][lane][j] : B[k][n], n = nt*16+(lane&15), k = ks*32+(lane>>4)*8+j
    for (int t = i; t < 98304; t += stride) {
      int j = t & 7, lane = (t >> 3) & 63, nt = (t >> 9) & 3, ks = (t >> 11) & 1, h = (t >> 12) & 7, sm = t >> 15;
      int k = ks * 32 + (lane >> 4) * 8 + j;
      int n = nt * 16 + (lane & 15);
      const float* W = (sm == 0) ? Wq : ((sm == 1) ? Wk : Wv);
      Wfrag[t] = f2bf(W[(h * 64 + n) * 64 + k]);
    }
    // Pfrag[mt8][ks2][lane][j] : A[m][k], m = mt*16+(lane&15), k = ks*32+(lane>>4)*8+j ; k=0 zero pad
    for (int t = i; t < 8192; t += stride) {
      int j = t & 7, lane = (t >> 3) & 63, ks = (t >> 9) & 1, mt = (t >> 10) & 7;
      int k = ks * 32 + (lane >> 4) * 8 + j;
      int m = mt * 16 + (lane & 15);
      Pfrag[t] = (k == 0) ? (unsigned short)0 : f2bf(P[(k - 1) * 128 + m] * (SQRT2F * LOG2E));
    }
  }
}

// ---------------- K2: fused mu -> (q,k,v) -> phi_q, phi_k (fp8) ; + last partial (phik^T @ V) ----------------
// Block = 256 thr (4 waves), block (h, t) owns 128 nodes. LDS 37888 B.
__global__ __launch_bounds__(256) void k2_mfma(const unsigned short* __restrict__ ubf,
                                               const unsigned short* __restrict__ Wfrag,
                                               const unsigned short* __restrict__ Pfrag,
                                               unsigned char* __restrict__ phiq, unsigned char* __restrict__ phik,
                                               unsigned short* __restrict__ part) {
  __shared__ short lds_raw[18944];             // 37888 B
  short* sbuf = lds_raw;                       // [(sm*4+w)*2304 + row*72 + col]
  float* sfront = (float*)(lds_raw + 18432);   // [(sm*4+w)*32 + row]
  short* kbufT = lds_raw;                      // post-barrier alias: [m*68 + nloc]
  short* vbufT = lds_raw + 8704;               // post-barrier alias: [d*72 + nloc]

  int w = threadIdx.x >> 6, lane = threadIdx.x & 63;
  int q = lane >> 4, l = lane & 15;
  int b = blockIdx.x;
  int h = b >> 8, t = b & 255;
  int n0 = t * 128 + w * 32;
  int r0 = h * 32768 + n0;

  s8v afr[2][2];
#pragma unroll
  for (int mt = 0; mt < 2; ++mt)
#pragma unroll
    for (int ks = 0; ks < 2; ++ks)
      afr[mt][ks] = *(const s8v*)(ubf + (size_t)(n0 + mt * 16 + l) * 64 + ks * 32 + q * 8);

  const s8v* Wf = (const s8v*)Wfrag;
  const s8v* Pf = (const s8v*)Pfrag;
  uint2 vkeep[2][4];

  // ---- Phase 1: three mu GEMMs + row nonlinearity; V -> vkeep regs ----
#pragma unroll
  for (int sm = 0; sm < 3; ++sm) {
    f4v acc[2][4];
#pragma unroll
    for (int mt = 0; mt < 2; ++mt)
#pragma unroll
      for (int nt = 0; nt < 4; ++nt) acc[mt][nt] = (f4v)(0.f);
#pragma unroll
    for (int ks = 0; ks < 2; ++ks)
#pragma unroll
      for (int nt = 0; nt < 4; ++nt) {
        s8v bf = Wf[(((sm * 8 + h) * 2 + ks) * 4 + nt) * 64 + lane];
#pragma unroll
        for (int mt = 0; mt < 2; ++mt)
          acc[mt][nt] = __builtin_amdgcn_mfma_f32_16x16x32_bf16(afr[mt][ks], bf, acc[mt][nt], 0, 0, 0);
      }
#pragma unroll
    for (int mt = 0; mt < 2; ++mt) {
      float rs[4];
#pragma unroll
      for (int reg = 0; reg < 4; ++reg) {
        float v0 = (l == 0) ? 0.f : acc[mt][0][reg];
        rs[reg] = v0 * v0 + acc[mt][1][reg] * acc[mt][1][reg] + acc[mt][2][reg] * acc[mt][2][reg] +
                  acc[mt][3][reg] * acc[mt][3][reg];
      }
#pragma unroll
      for (int reg = 0; reg < 4; ++reg) {
#pragma unroll
        for (int off = 1; off < 16; off <<= 1) rs[reg] += __shfl_xor(rs[reg], off, 64);
      }
      float vreg[4][4];
#pragma unroll
      for (int reg = 0; reg < 4; ++reg) {
        float x = fmaxf(fsqrt(rs[reg]), EPSF);
        float e = fexp2(x * LOG2E);
        float sh = 0.5f * (e - frcp(e));
        float ratio = sh * frcp(x);
        float sh2 = sh * sh;
        int row = mt * 16 + q * 4 + reg;
        if (sm == 2) {
          float tt2 = fsqrt(1.f + sh2);
#pragma unroll
          for (int nt = 0; nt < 4; ++nt) {
            float val = acc[mt][nt][reg] * ratio;
            if (l == 0 && nt == 0) val = tt2;
            vreg[nt][reg] = val;
          }
        } else {
          float lf = -sh2 * LOG2E - LOG2SQRT63;
          if (l == 0) sfront[(sm * 4 + w) * 32 + row] = lf;
#pragma unroll
          for (int nt = 0; nt < 4; ++nt) {
            float val = acc[mt][nt][reg] * ratio;
            if (l == 0 && nt == 0) val = 0.f;
            sbuf[(sm * 4 + w) * 2304 + row * 72 + nt * 16 + l] = (short)(__float_as_uint(val) >> 16);
          }
        }
      }
      if (sm == 2) {
#pragma unroll
        for (int nt = 0; nt < 4; ++nt) {
          vkeep[mt][nt].x = pack2(vreg[nt][0], vreg[nt][1]);
          vkeep[mt][nt].y = pack2(vreg[nt][2], vreg[nt][3]);
        }
      }
    }
  }

  // ---- Phase 2: phi^T GEMM ; phi = exp2(acc + lf) -> fp8 global ; keep phik bf16 regs ----
  uint2 keep0[8], keep1[8];
#pragma unroll
  for (int sm = 0; sm < 2; ++sm) {
    s8v bsf[2][2];
#pragma unroll
    for (int nt = 0; nt < 2; ++nt)
#pragma unroll
      for (int ks = 0; ks < 2; ++ks)
        bsf[nt][ks] = *(const s8v*)&sbuf[(sm * 4 + w) * 2304 + (nt * 16 + l) * 72 + ks * 32 + q * 8];
    float lf0 = sfront[(sm * 4 + w) * 32 + l];
    float lf1 = sfront[(sm * 4 + w) * 32 + 16 + l];
    unsigned char* dst = sm ? phik : phiq;
#pragma unroll
    for (int mt = 0; mt < 8; ++mt) {
      f4v a0 = (f4v)(0.f), a1 = (f4v)(0.f);
#pragma unroll
      for (int ks = 0; ks < 2; ++ks) {
        s8v ap = Pf[(mt * 2 + ks) * 64 + lane];
        a0 = __builtin_amdgcn_mfma_f32_16x16x32_bf16(ap, bsf[0][ks], a0, 0, 0, 0);
        a1 = __builtin_amdgcn_mfma_f32_16x16x32_bf16(ap, bsf[1][ks], a1, 0, 0, 0);
      }
      float v00 = fexp2(a0[0] + lf0), v01 = fexp2(a0[1] + lf0), v02 = fexp2(a0[2] + lf0), v03 = fexp2(a0[3] + lf0);
      float v10 = fexp2(a1[0] + lf1), v11 = fexp2(a1[1] + lf1), v12 = fexp2(a1[2] + lf1), v13 = fexp2(a1[3] + lf1);
      unsigned p0 = __builtin_amdgcn_cvt_pk_fp8_f32(v00, v01, 0, 0);
      p0 = __builtin_amdgcn_cvt_pk_fp8_f32(v02, v03, p0, 1);
      unsigned p1 = __builtin_amdgcn_cvt_pk_fp8_f32(v10, v11, 0, 0);
      p1 = __builtin_amdgcn_cvt_pk_fp8_f32(v12, v13, p1, 1);
      *(unsigned*)(dst + (size_t)(r0 + l) * 128 + mt * 16 + q * 4) = p0;
      *(unsigned*)(dst + (size_t)(r0 + 16 + l) * 128 + mt * 16 + q * 4) = p1;
      if (sm == 1) {
        keep0[mt].x = pack2(v00, v01); keep0[mt].y = pack2(v02, v03);
        keep1[mt].x = pack2(v10, v11); keep1[mt].y = pack2(v12, v13);
      }
    }
  }

  // ---- Fused GEMM over two 64-node halves: D[m][d] = sum_node phik[node][m] * V[node][d] ----
  f4v facc[2][4];
#pragma unroll
  for (int mtl = 0; mtl < 2; ++mtl)
#pragma unroll
    for (int nt = 0; nt < 4; ++nt) facc[mtl][nt] = (f4v)(0.f);

#pragma unroll
  for (int hf = 0; hf < 2; ++hf) {
    __syncthreads();
    if ((w >> 1) == hf) {
      int nd0 = (w & 1) * 32 + l, nd1 = nd0 + 16;
#pragma unroll
      for (int mt = 0; mt < 8; ++mt) {
        int m = mt * 16 + q * 4;
        kbufT[(m + 0) * 68 + nd0] = (short)(keep0[mt].x & 0xffffu);
        kbufT[(m + 1) * 68 + nd0] = (short)(keep0[mt].x >> 16);
        kbufT[(m + 2) * 68 + nd0] = (short)(keep0[mt].y & 0xffffu);
        kbufT[(m + 3) * 68 + nd0] = (short)(keep0[mt].y >> 16);
        kbufT[(m + 0) * 68 + nd1] = (short)(keep1[mt].x & 0xffffu);
        kbufT[(m + 1) * 68 + nd1] = (short)(keep1[mt].x >> 16);
        kbufT[(m + 2) * 68 + nd1] = (short)(keep1[mt].y & 0xffffu);
        kbufT[(m + 3) * 68 + nd1] = (short)(keep1[mt].y >> 16);
      }
#pragma unroll
      for (int mt = 0; mt < 2; ++mt)
#pragma unroll
        for (int nt = 0; nt < 4; ++nt)
          *(uint2*)&vbufT[(nt * 16 + l) * 72 + (w & 1) * 32 + mt * 16 + q * 4] = vkeep[mt][nt];
    }
    __syncthreads();
#pragma unroll
    for (int kc = 0; kc < 2; ++kc) {
      s8v bv[4];
#pragma unroll
      for (int nt = 0; nt < 4; ++nt)
        bv[nt] = *(const s8v*)&vbufT[(nt * 16 + l) * 72 + kc * 32 + q * 8];
      s8v av[2];
#pragma unroll
      for (int mtl = 0; mtl < 2; ++mtl) {
        const short* kb = &kbufT[((2 * w + mtl) * 16 + l) * 68 + kc * 32 + q * 8];
        union { s8v v; long long L[2]; } ua;
        ua.L[0] = *(const long long*)kb;
        ua.L[1] = *(const long long*)(kb + 4);
        av[mtl] = ua.v;
      }
#pragma unroll
      for (int mtl = 0; mtl < 2; ++mtl)
#pragma unroll
        for (int nt = 0; nt < 4; ++nt)
          facc[mtl][nt] = __builtin_amdgcn_mfma_f32_16x16x32_bf16(av[mtl], bv[nt], facc[mtl][nt], 0, 0, 0);
    }
  }

#pragma unroll
  for (int mtl = 0; mtl < 2; ++mtl)
#pragma unroll
    for (int nt = 0; nt < 4; ++nt) {
      uint2 pk;
      pk.x = pack2(facc[mtl][nt][0], facc[mtl][nt][1]);
      pk.y = pack2(facc[mtl][nt][2], facc[mtl][nt][3]);
      int d = nt * 16 + l;
      int m = (2 * w + mtl) * 16 + q * 4;
      *(uint2*)(part + ((size_t)((t * 8 + h) * 64 + d)) * 128 + m) = pk;
    }
}

// ---------------- K3p: reduce 256 bf16 partials -> lastB (bf8 e5m2, B-frag byte order) ----------------
__global__ __launch_bounds__(256) void k3p_pack(const unsigned* __restrict__ part32, unsigned char* __restrict__ lastB) {
  int t2 = blockIdx.x * 256 + threadIdx.x;  // 32768 = h*4096 + d*64 + m/2
  float s0 = 0.f, s1 = 0.f;
#pragma unroll 32
  for (int c = 0; c < 256; ++c) {
    unsigned v = part32[((size_t)c << 12) + t2];
    s0 += __uint_as_float(v << 16);
    s1 += __uint_as_float(v & 0xffff0000u);
  }
  int m = (t2 & 63) * 2, d = (t2 >> 6) & 63, h = t2 >> 12;
  int ks = m >> 5, j = m & 7, qq = (m >> 3) & 3;
  int lane = qq * 16 + (d & 15), nt = d >> 4;
  unsigned r = __builtin_amdgcn_cvt_pk_bf8_f32(s0, s1, 0, 0);
  *(unsigned short*)(lastB + ((((h * 4 + ks) * 4 + nt) * 64 + lane) << 3) + j) = (unsigned short)r;
}

// ---------------- K45: fused edge link-loss (b<2048) + zo GEMM/normalize (b>=2048) ----------------
// Edge blocks: 8 waves x 4 edges, fully-batched 8x1KB gathers; ea via device atomics + done-counter;
// the last edge block to finish writes the link_loss scalar. zo blocks: fp8xbf8 MFMA as before.
__global__ __launch_bounds__(512) void k45(const unsigned char* __restrict__ phiq,
                                           const unsigned char* __restrict__ phik,
                                           const unsigned char* __restrict__ lastB,
                                           const int* __restrict__ ei,
                                           float* __restrict__ ea, float* __restrict__ out) {
  __shared__ unsigned zbufT[8][64][18];
  __shared__ float epart[8];
  int b = blockIdx.x;
  int lane = threadIdx.x & 63, w = threadIdx.x >> 6;

  if (b < 2048) {
    // ---- edge path ----
    int wid = b * 8 + w;  // 16384 waves x 4 edges
    int e0 = wid * 4;
    int sA[4], dA[4];
#pragma unroll
    for (int j = 0; j < 4; ++j) { sA[j] = ei[e0 + j]; dA[j] = ei[NEDGES + e0 + j]; }
    uint4 qv[4], kv[4];
#pragma unroll
    for (int j = 0; j < 4; ++j) {
      qv[j] = *(const uint4*)(phiq + (size_t)dA[j] * 1024 + lane * 16);
      kv[j] = *(const uint4*)(phik + (size_t)sA[j] * 1024 + lane * 16);
    }
    float acc = 0.f;
#pragma unroll
    for (int j = 0; j < 4; ++j) {
      unsigned qs[4] = {qv[j].x, qv[j].y, qv[j].z, qv[j].w};
      unsigned ks[4] = {kv[j].x, kv[j].y, kv[j].z, kv[j].w};
#pragma unroll
      for (int p = 0; p < 4; ++p) {
        f2v q0 = __builtin_amdgcn_cvt_pk_f32_fp8(qs[p], 0);
        f2v q1 = __builtin_amdgcn_cvt_pk_f32_fp8(qs[p], 1);
        f2v k0 = __builtin_amdgcn_cvt_pk_f32_fp8(ks[p], 0);
        f2v k1 = __builtin_amdgcn_cvt_pk_f32_fp8(ks[p], 1);
        acc = fmaf(q0.x, k0.x, acc);
        acc = fmaf(q0.y, k0.y, acc);
        acc = fmaf(q1.x, k1.x, acc);
        acc = fmaf(q1.y, k1.y, acc);
      }
    }
#pragma unroll
    for (int o = 1; o < 64; o <<= 1) acc += __shfl_xor(acc, o, 64);
    if (lane == 0) epart[w] = acc;
    __syncthreads();
    if (threadIdx.x == 0) {
      float bs = epart[0] + epart[1] + epart[2] + epart[3] + epart[4] + epart[5] + epart[6] + epart[7];
      atomicAdd(ea, bs);
      __threadfence();
      unsigned prev = atomicAdd((unsigned*)(ea + 1), 1u);
      if (prev == 2047u) {
        float v = atomicAdd(ea, 0.f);  // atomic read-back: all prior adds visible
        out[(size_t)NNODES * 64] = v * (1.0f / 524288.0f);
      }
    }
    return;
  }

  // ---- zo path ----
  int q = lane >> 4, l = lane & 15;
  int n0 = (b - 2048) * 32;

  const long* Bf = (const long*)lastB;
  long bf[4][4];
#pragma unroll
  for (int ks = 0; ks < 4; ++ks)
#pragma unroll
    for (int nt = 0; nt < 4; ++nt) bf[ks][nt] = Bf[((w * 4 + ks) * 4 + nt) * 64 + lane];

  long af[2][4];
#pragma unroll
  for (int mt = 0; mt < 2; ++mt)
#pragma unroll
    for (int ks = 0; ks < 4; ++ks)
      af[mt][ks] = *(const long*)(phiq + (size_t)(8 * (n0 + mt * 16 + l) + w) * 128 + ks * 32 + q * 8);

  f4v acc[2][4];
#pragma unroll
  for (int mt = 0; mt < 2; ++mt)
#pragma unroll
    for (int nt = 0; nt < 4; ++nt) acc[mt][nt] = (f4v)(0.f);
#pragma unroll
  for (int ks = 0; ks < 4; ++ks)
#pragma unroll
    for (int nt = 0; nt < 4; ++nt)
#pragma unroll
      for (int mt = 0; mt < 2; ++mt)
        acc[mt][nt] = __builtin_amdgcn_mfma_f32_16x16x32_fp8_bf8(af[mt][ks], bf[ks][nt], acc[mt][nt], 0, 0, 0);

#pragma unroll
  for (int mt = 0; mt < 2; ++mt) {
    float rs[4];
#pragma unroll
    for (int reg = 0; reg < 4; ++reg) {
      float v0 = acc[mt][0][reg];
      float s0 = (l == 0) ? -v0 * v0 : v0 * v0;
      rs[reg] = s0 + acc[mt][1][reg] * acc[mt][1][reg] + acc[mt][2][reg] * acc[mt][2][reg] +
                acc[mt][3][reg] * acc[mt][3][reg];
    }
#pragma unroll
    for (int reg = 0; reg < 4; ++reg) {
#pragma unroll
      for (int off = 1; off < 16; off <<= 1) rs[reg] += __shfl_xor(rs[reg], off, 64);
    }
    float inv[4];
#pragma unroll
    for (int reg = 0; reg < 4; ++reg) inv[reg] = frcp(fsqrt(fabsf(rs[reg])));
#pragma unroll
    for (int nt = 0; nt < 4; ++nt) {
      uint2 pk;
      pk.x = pack2(acc[mt][nt][0] * inv[0], acc[mt][nt][1] * inv[1]);
      pk.y = pack2(acc[mt][nt][2] * inv[2], acc[mt][nt][3] * inv[3]);
      *(uint2*)&zbufT[w][nt * 16 + l][mt * 8 + q * 2] = pk;
    }
  }
  __syncthreads();

  int tid = threadIdx.x;
  int i = tid >> 4, dg = tid & 15;
  int i2 = i >> 1, sel = i & 1;
  float s[4] = {0.f, 0.f, 0.f, 0.f};
#pragma unroll
  for (int w2 = 0; w2 < 8; ++w2) {
#pragma unroll
    for (int j = 0; j < 4; ++j) {
      unsigned u = zbufT[w2][dg * 4 + j][i2];
      s[j] += bf2f((unsigned short)(sel ? (u >> 16) : (u & 0xffffu)));
    }
  }
  float m2 = 0.f;
#pragma unroll
  for (int j = 0; j < 4; ++j) {
    s[j] *= 0.125f;
    m2 += ((dg == 0 && j == 0) ? -s[j] * s[j] : s[j] * s[j]);
  }
#pragma unroll
  for (int off = 1; off < 16; off <<= 1) m2 += __shfl_xor(m2, off, 64);
  float inv = frcp(fsqrt(fabsf(m2)));
  float4 o = make_float4(s[0] * inv, s[1] * inv, s[2] * inv, s[3] * inv);
  *(float4*)(out + (size_t)(n0 + i) * 64 + dg * 4) = o;
}

// ---------------- launch ----------------
extern "C" void kernel_launch(void* const* d_in, const int* in_sizes, int n_in,
                              void* d_out, int out_size, void* d_ws, size_t ws_size,
                              hipStream_t stream) {
  const float* z  = (const float*)d_in[0];
  const float* Wq = (const float*)d_in[1];
  const float* Wk = (const float*)d_in[2];
  const float* Wv = (const float*)d_in[3];
  const float* P  = (const float*)d_in[4];
  const int* ei   = (const int*)d_in[5];
  char* ws = (char*)d_ws;
  unsigned short* Wfrag = (unsigned short*)(ws + OFF_WFRAG);
  unsigned char*  lastB = (unsigned char*)(ws + OFF_LASTB);  // sequenced reuse of Wfrag region
  unsigned short* Pfrag = (unsigned short*)(ws + OFF_PFRAG);
  float*          ea    = (float*)(ws + OFF_EA);
  unsigned short* ubf   = (unsigned short*)(ws + OFF_U);
  unsigned short* part  = (unsigned short*)(ws + OFF_PART);
  unsigned char*  phiq  = (unsigned char*)(ws + OFF_PHIQ);
  unsigned char*  phik  = (unsigned char*)(ws + OFF_PHIK);

  k01_prep<<<2048, 256, 0, stream>>>(z, ubf, Wq, Wk, Wv, P, Wfrag, Pfrag, ea);
  k2_mfma<<<2048, 256, 0, stream>>>(ubf, Wfrag, Pfrag, phiq, phik, part);
  k3p_pack<<<128, 256, 0, stream>>>((const unsigned*)part, lastB);
  k45<<<2048 + 1024, 512, 0, stream>>>(phiq, phik, lastB, ei, ea, (float*)d_out);
}